// Round 13
// baseline (1094.158 us; speedup 1.0000x reference)
//
#include <hip/hip_runtime.h>
#include <hip/hip_bf16.h>
#include <math.h>

#define NNODES 25000
#define NEDGES 400000
#define FIN0 64
#define DHID 128
#define NHEAD 4
#define CDIM 128
#define HC (NHEAD * CDIM)   // 512
#define NOUT 1664           // Q512 | K512 | V512 | S128
#define SCALE 0.088388347648318447f  // 1/sqrt(128)

// persistent attention geometry
#define ABLK 1024           // blocks (4/CU, co-resident)
#define WPB 4               // waves per block
#define MPW 7               // nodes per wave (1024*4*7 = 28672 >= 25000)
#define MAXT 16             // 16 tiles x 4 edges = 64 fast-path edges

typedef __attribute__((ext_vector_type(8))) short short8;
typedef __attribute__((ext_vector_type(4))) float floatx4;
typedef __attribute__((ext_vector_type(2))) float fx2;

typedef __attribute__((address_space(3))) unsigned int lds_u32_t;
typedef __attribute__((address_space(1))) const unsigned int glb_u32_t;

__device__ __forceinline__ void gload_lds16(const void* g, void* l) {
    __builtin_amdgcn_global_load_lds((glb_u32_t*)g, (lds_u32_t*)l, 16, 0, 0);
}

__device__ __forceinline__ short f2bf(float v) {
    unsigned u = __float_as_uint(v);
    u = (u + 0x7fffu + ((u >> 16) & 1u)) >> 16;   // RNE
    return (short)u;
}
__device__ __forceinline__ float bf2f(short s) {
    return __uint_as_float(((unsigned)(unsigned short)s) << 16);
}
__device__ __forceinline__ unsigned cvt_pk_bf16(float lo, float hi) {
    unsigned r;
    asm("v_cvt_pk_bf16_f32 %0, %1, %2" : "=v"(r) : "v"(lo), "v"(hi));
    return r;
}

// ---------------- utility kernels ----------------

// Coalesced transposed weight pack: WT[c][k] = (bf16)W[k][c], via 32x32 LDS tiles.
__global__ __launch_bounds__(256) void cvt_w_kernel(
    const float* __restrict__ Wq, const float* __restrict__ Wk,
    const float* __restrict__ Wv, const float* __restrict__ Ws,
    const float* __restrict__ bq, const float* __restrict__ bk,
    const float* __restrict__ bv, const float* __restrict__ bs,
    short* __restrict__ WT, float* __restrict__ bc, int fin)
{
    __shared__ float tile[32][33];
    int c0 = blockIdx.x * 32;
    int k0 = blockIdx.y * 32;
    int tx = threadIdx.x & 31, ty = threadIdx.x >> 5;   // 32 x 8

    const float* W; int ldw, cb;
    if (c0 < 512)       { W = Wq; ldw = 512; cb = c0; }
    else if (c0 < 1024) { W = Wk; ldw = 512; cb = c0 - 512; }
    else if (c0 < 1536) { W = Wv; ldw = 512; cb = c0 - 1024; }
    else                { W = Ws; ldw = 128; cb = c0 - 1536; }

#pragma unroll
    for (int i = 0; i < 4; ++i) {
        int k = k0 + ty + i * 8;
        tile[ty + i * 8][tx] = W[(size_t)k * ldw + cb + tx];
    }
    __syncthreads();
#pragma unroll
    for (int i = 0; i < 4; ++i) {
        int c = c0 + ty + i * 8;
        WT[(size_t)c * fin + k0 + tx] = f2bf(tile[tx][ty + i * 8]);
    }

    if (blockIdx.y == 0 && ty == 0) {
        int c = c0 + tx;
        float b;
        if (c < 512)       b = bq[c];
        else if (c < 1024) b = bk[c - 512];
        else if (c < 1536) b = bv[c - 1024];
        else               b = bs[c - 1536];
        bc[c] = b;
    }
}

// ---------------- CSR build ----------------

__global__ void count_kernel(const int* __restrict__ dst, int* __restrict__ deg, int e) {
    int i = blockIdx.x * blockDim.x + threadIdx.x;
    if (i < e) atomicAdd(&deg[dst[i]], 1);
}

__global__ __launch_bounds__(1024) void scan_kernel(
    const int* __restrict__ deg, int* __restrict__ offs,
    int* __restrict__ cnt, int n, int total) {
    __shared__ int sums[1024];
    int t = threadIdx.x;
    int chunk = (n + 1023) / 1024;
    int b = t * chunk;
    int e = min(b + chunk, n);
    int s = 0;
    for (int i = b; i < e; ++i) s += deg[i];
    sums[t] = s;
    __syncthreads();
    for (int o = 1; o < 1024; o <<= 1) {
        int v = (t >= o) ? sums[t - o] : 0;
        __syncthreads();
        sums[t] += v;
        __syncthreads();
    }
    int run = sums[t] - s;
    for (int i = b; i < e; ++i) {
        offs[i] = run;
        run += deg[i];
        cnt[i] = 0;
    }
    if (t == 0) offs[n] = total;
}

__global__ void scatter_kernel(const int* __restrict__ src, const int* __restrict__ dst,
                               const int* __restrict__ offs, int* __restrict__ cnt,
                               int* __restrict__ csr, int e) {
    int i = blockIdx.x * blockDim.x + threadIdx.x;
    if (i < e) {
        int d = dst[i];
        int pos = offs[d] + atomicAdd(&cnt[d], 1);
        csr[pos] = src[i];
    }
}

// ---------------- fused QKVS GEMM (bf16 MFMA) ----------------
// Same structure as round 12 (best so far); only K/V store layout changed:
// K8[h][node][128], V8[h][node][128] per-head sub-tables (3.2 MB each).
template<int FIN, bool CVT>
__global__ __launch_bounds__(256) void gemm_qkvs_mfma(
    const void* __restrict__ Xsrc, int n,
    const short* __restrict__ WT, const float* __restrict__ bc,
    short* __restrict__ Qb, unsigned char* __restrict__ K8,
    unsigned char* __restrict__ V8, short* __restrict__ Sb)
{
    constexpr int CPR16 = FIN / 8;          // 16B chunks per row
    constexpr int NK = FIN / 32;            // k-steps
    __shared__ short Xs[64 * FIN];          // linear, no pad

    int t = threadIdx.x;
    int row0 = blockIdx.x * 64;
    int l = t & 63, w = t >> 6;
    int wcol = blockIdx.y * 256 + w * 64;
    bool active = (wcol < NOUT);
    int lr = l & 15, lk = (l >> 4) * 8;
    int cg = (l >> 4) * 4;                  // col-group offset in epilogue

    if (CVT) {
        const float* xf = (const float*)Xsrc;
        for (int s = t; s < 64 * CPR16; s += 256) {
            int r = s / CPR16, c = s % CPR16;
            int cs = c ^ (r & 7);
            int gr = row0 + r;
            short8 v = {};
            if (gr < n) {
                float4 f0 = *(const float4*)&xf[(size_t)gr * FIN + cs * 8];
                float4 f1 = *(const float4*)&xf[(size_t)gr * FIN + cs * 8 + 4];
                v[0] = f2bf(f0.x); v[1] = f2bf(f0.y); v[2] = f2bf(f0.z); v[3] = f2bf(f0.w);
                v[4] = f2bf(f1.x); v[5] = f2bf(f1.y); v[6] = f2bf(f1.z); v[7] = f2bf(f1.w);
            }
            *(short8*)&Xs[s * 8] = v;
        }
    } else {
        const short* xb = (const short*)Xsrc;
#pragma unroll
        for (int it = 0; it < CPR16 / 4; ++it) {
            int seg = it * 4 + w;              // 1024B segment, wave-uniform
            int slot = seg * 64 + l;
            int r = slot / CPR16, c = slot % CPR16;
            int cs = c ^ (r & 7);
            const short* src = xb + (size_t)(row0 + r) * FIN + cs * 8;
            gload_lds16(src, &Xs[seg * 512]);  // dest: base + lane*16
        }
    }
    __syncthreads();
    if (!active) return;

    float4 bias[4];
#pragma unroll
    for (int ni = 0; ni < 4; ++ni)
        bias[ni] = *(const float4*)&bc[wcol + ni * 16 + cg];

    floatx4 acc[4][4] = {};
#pragma unroll
    for (int ks = 0; ks < NK; ++ks) {
        short8 b[4];
#pragma unroll
        for (int ni = 0; ni < 4; ++ni)
            b[ni] = *(const short8*)&WT[(size_t)(wcol + ni * 16 + lr) * FIN + ks * 32 + lk];
        short8 a[4];
        int q = ks * 4 + (l >> 4);
#pragma unroll
        for (int mi = 0; mi < 4; ++mi) {
            int row = mi * 16 + lr;
            a[mi] = *(const short8*)&Xs[(row * CPR16 + (q ^ (row & 7))) * 8];
        }
#pragma unroll
        for (int mi = 0; mi < 4; ++mi)
#pragma unroll
            for (int ni = 0; ni < 4; ++ni)
                acc[mi][ni] = __builtin_amdgcn_mfma_f32_16x16x32_bf16(
                    b[ni], a[mi], acc[mi][ni], 0, 0, 0);
    }

    int kind = (wcol < 512) ? 0 : (wcol < 1024) ? 1 : (wcol < 1536) ? 2 : 3;
#pragma unroll
    for (int mi = 0; mi < 4; ++mi) {
        int gr = row0 + mi * 16 + lr;
        if (gr >= n) continue;
#pragma unroll
        for (int ni = 0; ni < 4; ++ni) {
            int gc = wcol + ni * 16 + cg;
            float v0 = acc[mi][ni][0] + bias[ni].x;
            float v1 = acc[mi][ni][1] + bias[ni].y;
            float v2 = acc[mi][ni][2] + bias[ni].z;
            float v3 = acc[mi][ni][3] + bias[ni].w;
            if (kind == 0) {
                uint2 p;
                p.x = cvt_pk_bf16(v0, v1);
                p.y = cvt_pk_bf16(v2, v3);
                *(uint2*)&Qb[(size_t)gr * 512 + gc] = p;
            } else if (kind == 1) {
                int c = gc - 512;
                unsigned r8 = (unsigned)__builtin_amdgcn_cvt_pk_fp8_f32(v0, v1, 0, false);
                r8 = (unsigned)__builtin_amdgcn_cvt_pk_fp8_f32(v2, v3, r8, true);
                *(unsigned*)&K8[(((size_t)(c >> 7)) * NNODES + gr) * 128 + (c & 127)] = r8;
            } else if (kind == 2) {
                int c = gc - 1024;
                unsigned r8 = (unsigned)__builtin_amdgcn_cvt_pk_fp8_f32(v0, v1, 0, false);
                r8 = (unsigned)__builtin_amdgcn_cvt_pk_fp8_f32(v2, v3, r8, true);
                *(unsigned*)&V8[(((size_t)(c >> 7)) * NNODES + gr) * 128 + (c & 127)] = r8;
            } else {
                uint2 p;
                p.x = cvt_pk_bf16(v0, v1);
                p.y = cvt_pk_bf16(v2, v3);
                *(uint2*)&Sb[(size_t)gr * 128 + (gc - 1536)] = p;
            }
        }
    }
}

// ---------------- persistent phase-aligned attention ----------------
// 1024 blocks x 4 waves, all co-resident. Wave owns MPW nodes.
// For each head h: K-sweep over all my nodes (w -> LDS), sync,
// V-sweep (weighted accumulate), sync. Per-phase table = 3.2 MB < 4 MB L2/XCD.
// Lane mapping: group g = lane>>4 handles edge tile*4+g; i = lane&15 owns
// channels [8i, 8i+8) of head h (fp8, 8 B per lane; 128 B per edge-row).

__device__ __forceinline__ void unpack8(uint4 r, float* f) {
    f[0] = __uint_as_float(r.x << 16);
    f[1] = __uint_as_float(r.x & 0xffff0000u);
    f[2] = __uint_as_float(r.y << 16);
    f[3] = __uint_as_float(r.y & 0xffff0000u);
    f[4] = __uint_as_float(r.z << 16);
    f[5] = __uint_as_float(r.z & 0xffff0000u);
    f[6] = __uint_as_float(r.w << 16);
    f[7] = __uint_as_float(r.w & 0xffff0000u);
}

__device__ __forceinline__ void decf8(unsigned x, unsigned y, float* f) {
    fx2 a = __builtin_amdgcn_cvt_pk_f32_fp8(x, false);
    fx2 b = __builtin_amdgcn_cvt_pk_f32_fp8(x, true);
    fx2 c = __builtin_amdgcn_cvt_pk_f32_fp8(y, false);
    fx2 d = __builtin_amdgcn_cvt_pk_f32_fp8(y, true);
    f[0] = a[0]; f[1] = a[1]; f[2] = b[0]; f[3] = b[1];
    f[4] = c[0]; f[5] = c[1]; f[6] = d[0]; f[7] = d[1];
}

__device__ __forceinline__ float dotk(const float* q, uint2 kr) {
    float f[8];
    decf8(kr.x, kr.y, f);
    float p = 0.f;
#pragma unroll
    for (int j = 0; j < 8; ++j) p = fmaf(q[j], f[j], p);
    return p;
}

__device__ __forceinline__ float redu16(float p) {
#pragma unroll
    for (int o = 1; o < 16; o <<= 1) p += __shfl_xor(p, o);
    return p;
}

__global__ __launch_bounds__(256) void attn_kernel(
    const short* __restrict__ Qb, const unsigned char* __restrict__ K8,
    const unsigned char* __restrict__ V8, const int* __restrict__ offs,
    const int* __restrict__ csr, const short* __restrict__ Sb,
    short* __restrict__ Xo, int n)
{
    __shared__ float wlds[WPB][MPW][MAXT * 4];
    __shared__ float om[WPB][MPW][128];

    int t = threadIdx.x;
    int w = t >> 6, l = t & 63;
    int g = l >> 4, i = l & 15;
    int wid = blockIdx.x * WPB + w;
    int nbase = wid * MPW;

    for (int h = 0; h < NHEAD; ++h) {
        const unsigned char* Kt = K8 + (size_t)h * n * 128;
        const unsigned char* Vt = V8 + (size_t)h * n * 128;

        // ---- K sweep: all my nodes, this head's 3.2MB K table ----
        for (int m = 0; m < MPW; ++m) {
            int node = nbase + m;
            if (node >= n) break;
            int beg = offs[node], end = offs[node + 1];
            float qf[8];
            {
                uint4 qr = *(const uint4*)&Qb[(size_t)node * 512 + h * 128 + i * 8];
                unpack8(qr, qf);
            }
            int ntile = min((end - beg + 3) >> 2, MAXT);
            for (int tt = 0; tt < ntile; ++tt) {
                int e = beg + tt * 4 + g;
                int valid = (e < end);
                int s = valid ? csr[e] : 0;
                uint2 kr = *(const uint2*)(Kt + (size_t)s * 128 + i * 8);
                float p = redu16(dotk(qf, kr));
                float ww = valid ? __expf(p * SCALE) : 0.f;
                if (i == 0) wlds[w][m][tt * 4 + g] = ww;
            }
        }
        __syncthreads();

        // ---- V sweep: this head's 3.2MB V table ----
        for (int m = 0; m < MPW; ++m) {
            int node = nbase + m;
            if (node >= n) break;
            int beg = offs[node], end = offs[node + 1];
            float acc[8] = {};
            float dl = 0.f;
            int ntile = min((end - beg + 3) >> 2, MAXT);
            for (int tt = 0; tt < ntile; ++tt) {
                int e = beg + tt * 4 + g;
                int valid = (e < end);
                int s = valid ? csr[e] : 0;
                float ww = wlds[w][m][tt * 4 + g];          // 0 for invalid
                uint2 vr = *(const uint2*)(Vt + (size_t)s * 128 + i * 8);
                float vf[8];
                decf8(vr.x, vr.y, vf);
                dl += ww;
#pragma unroll
                for (int j = 0; j < 8; ++j) acc[j] = fmaf(ww, vf[j], acc[j]);
            }
            // rare slow path: edges beyond MAXT*4
            if (end - beg > MAXT * 4) {
                float qf[8];
                uint4 qr = *(const uint4*)&Qb[(size_t)node * 512 + h * 128 + i * 8];
                unpack8(qr, qf);
                for (int e0 = beg + MAXT * 4; e0 < end; e0 += 4) {
                    int e = e0 + g;
                    int valid = (e < end);
                    int s = valid ? csr[e] : 0;
                    uint2 kr = *(const uint2*)(Kt + (size_t)s * 128 + i * 8);
                    float p = redu16(dotk(qf, kr));
                    float ww = valid ? __expf(p * SCALE) : 0.f;
                    uint2 vr = *(const uint2*)(Vt + (size_t)s * 128 + i * 8);
                    float vf[8];
                    decf8(vr.x, vr.y, vf);
                    dl += ww;
#pragma unroll
                    for (int j = 0; j < 8; ++j) acc[j] = fmaf(ww, vf[j], acc[j]);
                }
            }
            // reduce across the 4 edge-groups (lanes l, l^16, l^32, l^48)
#pragma unroll
            for (int j = 0; j < 8; ++j) {
                acc[j] += __shfl_xor(acc[j], 16);
                acc[j] += __shfl_xor(acc[j], 32);
            }
            dl += __shfl_xor(dl, 16);
            dl += __shfl_xor(dl, 32);
            float inv = (dl > 0.f) ? 1.f / dl : 0.f;
            if (g == 0) {
#pragma unroll
                for (int j = 0; j < 8; ++j) {
                    float v = acc[j] * inv;
                    if (h == 0) om[w][m][i * 8 + j] = v;
                    else        om[w][m][i * 8 + j] += v;
                }
            }
        }
        __syncthreads();
    }

    // ---- epilogue: head-mean + skip + relu -> bf16 ----
    for (int m = 0; m < MPW; ++m) {
        int node = nbase + m;
        if (node >= n) break;
        if (g == 0) {
            float sf[8];
            uint4 sr = *(const uint4*)&Sb[(size_t)node * 128 + i * 8];
            unpack8(sr, sf);
            short8 o;
#pragma unroll
            for (int j = 0; j < 8; ++j)
                o[j] = f2bf(fmaxf(om[w][m][i * 8 + j] * 0.25f + sf[j], 0.f));
            *(short8*)&Xo[(size_t)node * 128 + i * 8] = o;
        }
    }
}

// ---------------- column sum + final sigmoid ----------------
__global__ void colsum_kernel(const short* __restrict__ X, float* __restrict__ g, int n) {
    int c = threadIdx.x;  // 128 threads
    int rpb = (n + gridDim.x - 1) / gridDim.x;
    int r0 = blockIdx.x * rpb;
    int r1 = min(r0 + rpb, n);
    float acc = 0.f;
    for (int r = r0; r < r1; ++r) acc += bf2f(X[r * DHID + c]);
    atomicAdd(&g[c], acc);
}

__global__ void final_kernel(const float* __restrict__ g, const float* __restrict__ Wfc,
                             const float* __restrict__ bfc, float* __restrict__ out, float invn) {
    __shared__ float red[128];
    int t = threadIdx.x;
    red[t] = g[t] * invn * Wfc[t];
    __syncthreads();
    for (int o = 64; o > 0; o >>= 1) {
        if (t < o) red[t] += red[t + o];
        __syncthreads();
    }
    if (t == 0) {
        float z = red[0] + bfc[0];
        out[0] = 1.f / (1.f + expf(-z));
    }
}

// ---------------- host ----------------

extern "C" void kernel_launch(void* const* d_in, const int* in_sizes, int n_in,
                              void* d_out, int out_size, void* d_ws, size_t ws_size,
                              hipStream_t stream) {
    const int N = NNODES, E = NEDGES;
    const float* x = (const float*)d_in[0];
    const int* ei = (const int*)d_in[1];
    const int* src = ei;
    const int* dst = ei + E;
    const float* Wfc = (const float*)d_in[26];
    const float* bfc = (const float*)d_in[27];

    size_t off = 0;
    auto alloc = [&](size_t bytes) -> char* {
        char* p = (char*)d_ws + off;
        off += (bytes + 255) & ~(size_t)255;
        return p;
    };
    int* deg   = (int*)alloc((size_t)N * 4);
    int* cnt   = (int*)alloc((size_t)N * 4);
    int* offs  = (int*)alloc((size_t)(N + 1) * 4);
    int* csr   = (int*)alloc((size_t)E * 4);
    short* Qb  = (short*)alloc((size_t)N * HC * 2);
    unsigned char* K8 = (unsigned char*)alloc((size_t)N * 512);
    unsigned char* V8 = (unsigned char*)alloc((size_t)N * 512);
    short* Sb  = (short*)alloc((size_t)N * DHID * 2);
    short* xb1 = (short*)alloc((size_t)(N + 64) * DHID * 2);
    short* xb2 = (short*)alloc((size_t)(N + 64) * DHID * 2);
    short* WT  = (short*)alloc((size_t)NOUT * DHID * 2);
    float* bc  = (float*)alloc((size_t)NOUT * 4);
    float* g   = (float*)alloc(128 * 4);

    hipMemsetAsync(deg, 0, (size_t)N * 4, stream);
    hipMemsetAsync(g, 0, 128 * 4, stream);

    count_kernel<<<(E + 255) / 256, 256, 0, stream>>>(dst, deg, E);
    scan_kernel<<<1, 1024, 0, stream>>>(deg, offs, cnt, N, E);
    scatter_kernel<<<(E + 255) / 256, 256, 0, stream>>>(src, dst, offs, cnt, csr, E);

    int gx = (N + 63) / 64;

    const void* xin = x;             // layer 0 reads fp32 x directly
    short* xouts[3] = { xb1, xb2, xb1 };
    for (int l = 0; l < 3; ++l) {
        int fin = (l == 0) ? FIN0 : DHID;
        const float* Wq = (const float*)d_in[2 + l * 8 + 0];
        const float* bq = (const float*)d_in[2 + l * 8 + 1];
        const float* Wk = (const float*)d_in[2 + l * 8 + 2];
        const float* bk = (const float*)d_in[2 + l * 8 + 3];
        const float* Wv = (const float*)d_in[2 + l * 8 + 4];
        const float* bv = (const float*)d_in[2 + l * 8 + 5];
        const float* Wss= (const float*)d_in[2 + l * 8 + 6];
        const float* bs = (const float*)d_in[2 + l * 8 + 7];

        dim3 wgrid(NOUT / 32, fin / 32);
        cvt_w_kernel<<<wgrid, 256, 0, stream>>>(
            Wq, Wk, Wv, Wss, bq, bk, bv, bs, WT, bc, fin);

        dim3 ggrid(gx, 7);
        if (l == 0)
            gemm_qkvs_mfma<64, true><<<ggrid, 256, 0, stream>>>(xin, N, WT, bc, Qb, K8, V8, Sb);
        else
            gemm_qkvs_mfma<128, false><<<ggrid, 256, 0, stream>>>(xin, N, WT, bc, Qb, K8, V8, Sb);
        attn_kernel<<<ABLK, 256, 0, stream>>>(Qb, K8, V8, offs, csr, Sb, xouts[l], N);
        xin = xouts[l];
    }

    colsum_kernel<<<256, 128, 0, stream>>>(xb1, g, N);
    final_kernel<<<1, 128, 0, stream>>>(g, Wfc, bfc, (float*)d_out, 1.0f / N);
}

// Round 14
// 515.479 us; speedup vs baseline: 2.1226x; 2.1226x over previous
//
#include <hip/hip_runtime.h>
#include <hip/hip_bf16.h>
#include <math.h>

#define NNODES 25000
#define NEDGES 400000
#define FIN0 64
#define DHID 128
#define NHEAD 4
#define CDIM 128
#define HC (NHEAD * CDIM)   // 512
#define NOUT 1664           // Q512 | K512 | V512 | S128
#define SCALE 0.088388347648318447f  // 1/sqrt(128)

typedef __attribute__((ext_vector_type(8))) short short8;
typedef __attribute__((ext_vector_type(4))) float floatx4;
typedef __attribute__((ext_vector_type(2))) float fx2;

typedef __attribute__((address_space(3))) unsigned int lds_u32_t;
typedef __attribute__((address_space(1))) const unsigned int glb_u32_t;

__device__ __forceinline__ void gload_lds16(const void* g, void* l) {
    __builtin_amdgcn_global_load_lds((glb_u32_t*)g, (lds_u32_t*)l, 16, 0, 0);
}

__device__ __forceinline__ short f2bf(float v) {
    unsigned u = __float_as_uint(v);
    u = (u + 0x7fffu + ((u >> 16) & 1u)) >> 16;   // RNE
    return (short)u;
}
__device__ __forceinline__ float bf2f(short s) {
    return __uint_as_float(((unsigned)(unsigned short)s) << 16);
}
__device__ __forceinline__ unsigned cvt_pk_bf16(float lo, float hi) {
    unsigned r;
    asm("v_cvt_pk_bf16_f32 %0, %1, %2" : "=v"(r) : "v"(lo), "v"(hi));
    return r;
}

struct LayerPtrs {
    const float* W[3][8];   // Wq,bq,Wk,bk,Wv,bv,Ws,bs per layer
    short* WT[3];
    float* bc[3];
};

// ---------------- weight pack: all 3 layers, one launch ----------------
// WT[c][k] = (bf16)W[k][c] via 32x32 LDS tile transpose; bc = concat biases.
__global__ __launch_bounds__(256) void cvt_w_all(LayerPtrs P) {
    __shared__ float tile[32][33];
    int layer = blockIdx.z;
    int fin = (layer == 0) ? FIN0 : DHID;
    int k0 = blockIdx.y * 32;
    if (k0 >= fin) return;
    int c0 = blockIdx.x * 32;
    int tx = threadIdx.x & 31, ty = threadIdx.x >> 5;   // 32 x 8

    const float* W; int ldw, cb;
    if (c0 < 512)       { W = P.W[layer][0]; ldw = 512; cb = c0; }
    else if (c0 < 1024) { W = P.W[layer][2]; ldw = 512; cb = c0 - 512; }
    else if (c0 < 1536) { W = P.W[layer][4]; ldw = 512; cb = c0 - 1024; }
    else                { W = P.W[layer][6]; ldw = 128; cb = c0 - 1536; }

#pragma unroll
    for (int i = 0; i < 4; ++i) {
        int k = k0 + ty + i * 8;
        tile[ty + i * 8][tx] = W[(size_t)k * ldw + cb + tx];
    }
    __syncthreads();
    short* WT = P.WT[layer];
#pragma unroll
    for (int i = 0; i < 4; ++i) {
        int c = c0 + ty + i * 8;
        WT[(size_t)c * fin + k0 + tx] = f2bf(tile[tx][ty + i * 8]);
    }

    if (blockIdx.y == 0 && ty == 0) {
        int c = c0 + tx;
        float b;
        if (c < 512)       b = P.W[layer][1][c];
        else if (c < 1024) b = P.W[layer][3][c - 512];
        else if (c < 1536) b = P.W[layer][5][c - 1024];
        else               b = P.W[layer][7][c - 1536];
        P.bc[layer][c] = b;
    }
}

// ---------------- CSR build ----------------

__global__ void count_kernel(const int* __restrict__ dst, int* __restrict__ deg, int e) {
    int i = blockIdx.x * blockDim.x + threadIdx.x;
    if (i < e) atomicAdd(&deg[dst[i]], 1);
}

__global__ __launch_bounds__(1024) void scan_kernel(
    const int* __restrict__ deg, int* __restrict__ offs,
    int* __restrict__ cnt, int n, int total) {
    __shared__ int sums[1024];
    int t = threadIdx.x;
    int chunk = (n + 1023) / 1024;
    int b = t * chunk;
    int e = min(b + chunk, n);
    int s = 0;
    for (int i = b; i < e; ++i) s += deg[i];
    sums[t] = s;
    __syncthreads();
    for (int o = 1; o < 1024; o <<= 1) {
        int v = (t >= o) ? sums[t - o] : 0;
        __syncthreads();
        sums[t] += v;
        __syncthreads();
    }
    int run = sums[t] - s;
    for (int i = b; i < e; ++i) {
        offs[i] = run;
        run += deg[i];
        cnt[i] = 0;
    }
    if (t == 0) offs[n] = total;
}

__global__ void scatter_kernel(const int* __restrict__ src, const int* __restrict__ dst,
                               const int* __restrict__ offs, int* __restrict__ cnt,
                               int* __restrict__ csr, int e) {
    int i = blockIdx.x * blockDim.x + threadIdx.x;
    if (i < e) {
        int d = dst[i];
        int pos = offs[d] + atomicAdd(&cnt[d], 1);
        csr[pos] = src[i];
    }
}

// ---------------- fused QKVS GEMM (bf16 MFMA) ----------------
// C = X[n x FIN] @ Wcat[FIN x 1664] + bcat.
// Block: 64 rows x 256 cols, 4 waves; wave = 64x64 (4x4 frags).
// X staged in LINEAR LDS via global_load_lds (16B) with XOR chunk-swizzle.
// mfma(b,a) => lane holds 4 consecutive output cols of one row.
// KV epilogue: wave-local LDS repack (4x4 piece transpose) -> one uint4
// store per lane = 16 rows x 64B full lines (was 16B quarter-lines).
template<int FIN, bool CVT>
__global__ __launch_bounds__(256) void gemm_qkvs_mfma(
    const void* __restrict__ Xsrc, int n,
    const short* __restrict__ WT, const float* __restrict__ bc,
    short* __restrict__ Qb, unsigned char* __restrict__ KV,
    short* __restrict__ Sb)
{
    constexpr int CPR16 = FIN / 8;          // 16B chunks per row
    constexpr int NK = FIN / 32;            // k-steps
    __shared__ short Xs[64 * FIN];          // linear, no pad
    __shared__ unsigned pack[4][256];       // per-wave repack buffer (1KB/wave)

    int t = threadIdx.x;
    int row0 = blockIdx.x * 64;
    int l = t & 63, w = t >> 6;
    int wcol = blockIdx.y * 256 + w * 64;
    bool active = (wcol < NOUT);
    int lr = l & 15, lk = (l >> 4) * 8;
    int cg = (l >> 4) * 4;                  // col-group offset in epilogue

    if (CVT) {
        // fp32 input -> bf16, manual staging with swizzled placement
        const float* xf = (const float*)Xsrc;
        for (int s = t; s < 64 * CPR16; s += 256) {
            int r = s / CPR16, c = s % CPR16;
            int cs = c ^ (r & 7);
            int gr = row0 + r;
            short8 v = {};
            if (gr < n) {
                float4 f0 = *(const float4*)&xf[(size_t)gr * FIN + cs * 8];
                float4 f1 = *(const float4*)&xf[(size_t)gr * FIN + cs * 8 + 4];
                v[0] = f2bf(f0.x); v[1] = f2bf(f0.y); v[2] = f2bf(f0.z); v[3] = f2bf(f0.w);
                v[4] = f2bf(f1.x); v[5] = f2bf(f1.y); v[6] = f2bf(f1.z); v[7] = f2bf(f1.w);
            }
            *(short8*)&Xs[s * 8] = v;
        }
    } else {
        // bf16 input (pad rows exist): async global->LDS, 16B per lane
        const short* xb = (const short*)Xsrc;
#pragma unroll
        for (int it = 0; it < CPR16 / 4; ++it) {
            int seg = it * 4 + w;              // 1024B segment, wave-uniform
            int slot = seg * 64 + l;
            int r = slot / CPR16, c = slot % CPR16;
            int cs = c ^ (r & 7);
            const short* src = xb + (size_t)(row0 + r) * FIN + cs * 8;
            gload_lds16(src, &Xs[seg * 512]);  // dest: base + lane*16
        }
    }
    __syncthreads();
    if (!active) return;

    float4 bias[4];
#pragma unroll
    for (int ni = 0; ni < 4; ++ni)
        bias[ni] = *(const float4*)&bc[wcol + ni * 16 + cg];

    floatx4 acc[4][4] = {};
#pragma unroll
    for (int ks = 0; ks < NK; ++ks) {
        short8 b[4];
#pragma unroll
        for (int ni = 0; ni < 4; ++ni)
            b[ni] = *(const short8*)&WT[(size_t)(wcol + ni * 16 + lr) * FIN + ks * 32 + lk];
        short8 a[4];
        int q = ks * 4 + (l >> 4);             // chunk col of this lane's A slice
#pragma unroll
        for (int mi = 0; mi < 4; ++mi) {
            int row = mi * 16 + lr;
            a[mi] = *(const short8*)&Xs[(row * CPR16 + (q ^ (row & 7))) * 8];
        }
#pragma unroll
        for (int mi = 0; mi < 4; ++mi)
#pragma unroll
            for (int ni = 0; ni < 4; ++ni)
                acc[mi][ni] = __builtin_amdgcn_mfma_f32_16x16x32_bf16(
                    b[ni], a[mi], acc[mi][ni], 0, 0, 0);
    }

    int kind = (wcol < 512) ? 0 : (wcol < 1024) ? 1 : (wcol < 1536) ? 2 : 3;
    if (kind == 1 || kind == 2) {
        // fp8 K/V with full-line store repack
        int base = (kind == 1) ? (wcol - 512) : (512 + wcol - 1024);
        int q = l >> 4;
#pragma unroll
        for (int mi = 0; mi < 4; ++mi) {
            unsigned r8[4];
#pragma unroll
            for (int ni = 0; ni < 4; ++ni) {
                float v0 = acc[mi][ni][0] + bias[ni].x;
                float v1 = acc[mi][ni][1] + bias[ni].y;
                float v2 = acc[mi][ni][2] + bias[ni].z;
                float v3 = acc[mi][ni][3] + bias[ni].w;
                unsigned r = (unsigned)__builtin_amdgcn_cvt_pk_fp8_f32(v0, v1, 0, false);
                r8[ni] = (unsigned)__builtin_amdgcn_cvt_pk_fp8_f32(v2, v3, r, true);
            }
            *(uint4*)&pack[w][l * 4] = make_uint4(r8[0], r8[1], r8[2], r8[3]);
            unsigned u0 = pack[w][(lr     ) * 4 + q];
            unsigned u1 = pack[w][(lr + 16) * 4 + q];
            unsigned u2 = pack[w][(lr + 32) * 4 + q];
            unsigned u3 = pack[w][(lr + 48) * 4 + q];
            int row = row0 + mi * 16 + lr;
            if (row < n)
                *(uint4*)&KV[(size_t)row * 1024 + base + q * 16] =
                    make_uint4(u0, u1, u2, u3);
        }
    } else {
#pragma unroll
        for (int mi = 0; mi < 4; ++mi) {
            int gr = row0 + mi * 16 + lr;
            if (gr >= n) continue;
#pragma unroll
            for (int ni = 0; ni < 4; ++ni) {
                int gc = wcol + ni * 16 + cg;
                float v0 = acc[mi][ni][0] + bias[ni].x;
                float v1 = acc[mi][ni][1] + bias[ni].y;
                float v2 = acc[mi][ni][2] + bias[ni].z;
                float v3 = acc[mi][ni][3] + bias[ni].w;
                uint2 p;
                p.x = cvt_pk_bf16(v0, v1);
                p.y = cvt_pk_bf16(v2, v3);
                if (kind == 0) *(uint2*)&Qb[(size_t)gr * 512 + gc] = p;
                else           *(uint2*)&Sb[(size_t)gr * 128 + (gc - 1536)] = p;
            }
        }
    }
}

// ---------------- fused attention + head-mean + skip + relu (r12) ----------------
// One wave per dst node, all 4 heads. Lane i owns channels [8i,8i+8).
// K/V fp8, split halves: K at KV[s*1024 + lane*8], V at +512.
// No online-max: alpha bounded so plain exp(alpha) accumulation is safe.

__device__ __forceinline__ void unpack8(uint4 r, float* f) {
    f[0] = __uint_as_float(r.x << 16);
    f[1] = __uint_as_float(r.x & 0xffff0000u);
    f[2] = __uint_as_float(r.y << 16);
    f[3] = __uint_as_float(r.y & 0xffff0000u);
    f[4] = __uint_as_float(r.z << 16);
    f[5] = __uint_as_float(r.z & 0xffff0000u);
    f[6] = __uint_as_float(r.w << 16);
    f[7] = __uint_as_float(r.w & 0xffff0000u);
}

__device__ __forceinline__ void decf8(unsigned x, unsigned y, float* f) {
    fx2 a = __builtin_amdgcn_cvt_pk_f32_fp8(x, false);
    fx2 b = __builtin_amdgcn_cvt_pk_f32_fp8(x, true);
    fx2 c = __builtin_amdgcn_cvt_pk_f32_fp8(y, false);
    fx2 d = __builtin_amdgcn_cvt_pk_f32_fp8(y, true);
    f[0] = a[0]; f[1] = a[1]; f[2] = b[0]; f[3] = b[1];
    f[4] = c[0]; f[5] = c[1]; f[6] = d[0]; f[7] = d[1];
}

__device__ __forceinline__ float dotk(const float* q, uint2 kr) {
    float f[8];
    decf8(kr.x, kr.y, f);
    float p = 0.f;
#pragma unroll
    for (int j = 0; j < 8; ++j) p = fmaf(q[j], f[j], p);
    return p;
}

__device__ __forceinline__ void accv(float& d, float* acc, float p, uint2 vr) {
    float vf[8];
    decf8(vr.x, vr.y, vf);
    float w = __expf(p * SCALE);
    d += w;
#pragma unroll
    for (int j = 0; j < 8; ++j) acc[j] = fmaf(w, vf[j], acc[j]);
}

__device__ __forceinline__ float redu16(float p) {
#pragma unroll
    for (int o = 1; o < 16; o <<= 1) p += __shfl_xor(p, o);
    return p;
}

__global__ __launch_bounds__(256) void attn_kernel(
    const short* __restrict__ Qb, const unsigned char* __restrict__ KV,
    const int* __restrict__ offs, const int* __restrict__ csr,
    const short* __restrict__ Sb, short* __restrict__ Xo, int n)
{
    int node = (blockIdx.x * blockDim.x + threadIdx.x) >> 6;
    if (node >= n) return;
    int lane = threadIdx.x & 63;

    float qf[8];
    {
        uint4 qr = *(const uint4*)&Qb[(size_t)node * 512 + lane * 8];
        unpack8(qr, qf);
    }

    int beg = offs[node], end = offs[node + 1];
    float d = 0.f;
    float acc[8] = {};

    int e = beg;
    for (; e + 7 < end; e += 8) {
        uint2 kr[8], vr[8];
#pragma unroll
        for (int j = 0; j < 8; ++j) {
            int s = csr[e + j];
            const unsigned char* b = KV + (size_t)s * 1024 + lane * 8;
            kr[j] = *(const uint2*)b;
            vr[j] = *(const uint2*)(b + 512);
        }
        float p[8];
#pragma unroll
        for (int j = 0; j < 8; ++j) p[j] = dotk(qf, kr[j]);
#pragma unroll
        for (int j = 0; j < 8; ++j) p[j] = redu16(p[j]);
#pragma unroll
        for (int j = 0; j < 8; ++j) accv(d, acc, p[j], vr[j]);
    }
    for (; e + 3 < end; e += 4) {
        uint2 kr[4], vr[4];
#pragma unroll
        for (int j = 0; j < 4; ++j) {
            int s = csr[e + j];
            const unsigned char* b = KV + (size_t)s * 1024 + lane * 8;
            kr[j] = *(const uint2*)b;
            vr[j] = *(const uint2*)(b + 512);
        }
        float p[4];
#pragma unroll
        for (int j = 0; j < 4; ++j) p[j] = dotk(qf, kr[j]);
#pragma unroll
        for (int j = 0; j < 4; ++j) p[j] = redu16(p[j]);
#pragma unroll
        for (int j = 0; j < 4; ++j) accv(d, acc, p[j], vr[j]);
    }
    for (; e < end; ++e) {
        int s = csr[e];
        const unsigned char* b = KV + (size_t)s * 1024 + lane * 8;
        uint2 kr = *(const uint2*)b;
        uint2 vr = *(const uint2*)(b + 512);
        float p = redu16(dotk(qf, kr));
        accv(d, acc, p, vr);
    }

    float inv = (d > 0.f) ? 1.f / d : 0.f;
#pragma unroll
    for (int j = 0; j < 8; ++j) acc[j] *= inv;

    // head mean across the 4 heads (lanes l, l^16, l^32, l^48 share channel)
#pragma unroll
    for (int j = 0; j < 8; ++j) {
        acc[j] += __shfl_xor(acc[j], 16);
        acc[j] += __shfl_xor(acc[j], 32);
    }

    if (lane < 16) {
        int c0 = lane * 8;
        float sf[8];
        uint4 sr = *(const uint4*)&Sb[(size_t)node * 128 + c0];
        unpack8(sr, sf);
        short8 o;
#pragma unroll
        for (int j = 0; j < 8; ++j)
            o[j] = f2bf(fmaxf(acc[j] * 0.25f + sf[j], 0.f));
        *(short8*)&Xo[(size_t)node * 128 + c0] = o;
    }
}

// ---------------- column sum + final sigmoid ----------------
__global__ void colsum_kernel(const short* __restrict__ X, float* __restrict__ g, int n) {
    int c = threadIdx.x;  // 128 threads
    int rpb = (n + gridDim.x - 1) / gridDim.x;
    int r0 = blockIdx.x * rpb;
    int r1 = min(r0 + rpb, n);
    float acc = 0.f;
    for (int r = r0; r < r1; ++r) acc += bf2f(X[r * DHID + c]);
    atomicAdd(&g[c], acc);
}

__global__ void final_kernel(const float* __restrict__ g, const float* __restrict__ Wfc,
                             const float* __restrict__ bfc, float* __restrict__ out, float invn) {
    __shared__ float red[128];
    int t = threadIdx.x;
    red[t] = g[t] * invn * Wfc[t];
    __syncthreads();
    for (int o = 64; o > 0; o >>= 1) {
        if (t < o) red[t] += red[t + o];
        __syncthreads();
    }
    if (t == 0) {
        float z = red[0] + bfc[0];
        out[0] = 1.f / (1.f + expf(-z));
    }
}

// ---------------- host ----------------

extern "C" void kernel_launch(void* const* d_in, const int* in_sizes, int n_in,
                              void* d_out, int out_size, void* d_ws, size_t ws_size,
                              hipStream_t stream) {
    const int N = NNODES, E = NEDGES;
    const float* x = (const float*)d_in[0];
    const int* ei = (const int*)d_in[1];
    const int* src = ei;
    const int* dst = ei + E;
    const float* Wfc = (const float*)d_in[26];
    const float* bfc = (const float*)d_in[27];

    size_t off = 0;
    auto alloc = [&](size_t bytes) -> char* {
        char* p = (char*)d_ws + off;
        off += (bytes + 255) & ~(size_t)255;
        return p;
    };
    int* deg   = (int*)alloc((size_t)N * 4);
    int* cnt   = (int*)alloc((size_t)N * 4);
    int* offs  = (int*)alloc((size_t)(N + 1) * 4);
    int* csr   = (int*)alloc((size_t)E * 4);
    short* Qb  = (short*)alloc((size_t)N * HC * 2);
    unsigned char* KV = (unsigned char*)alloc((size_t)N * 1024);
    short* Sb  = (short*)alloc((size_t)N * DHID * 2);
    short* xb1 = (short*)alloc((size_t)(N + 64) * DHID * 2);
    short* xb2 = (short*)alloc((size_t)(N + 64) * DHID * 2);
    LayerPtrs P;
    for (int l = 0; l < 3; ++l) {
        for (int i = 0; i < 8; ++i) P.W[l][i] = (const float*)d_in[2 + l * 8 + i];
        P.WT[l] = (short*)alloc((size_t)NOUT * DHID * 2);
        P.bc[l] = (float*)alloc((size_t)NOUT * 4);
    }
    float* g   = (float*)alloc(128 * 4);

    hipMemsetAsync(deg, 0, (size_t)N * 4, stream);
    hipMemsetAsync(g, 0, 128 * 4, stream);

    count_kernel<<<(E + 255) / 256, 256, 0, stream>>>(dst, deg, E);
    scan_kernel<<<1, 1024, 0, stream>>>(deg, offs, cnt, N, E);
    scatter_kernel<<<(E + 255) / 256, 256, 0, stream>>>(src, dst, offs, cnt, csr, E);

    // all weight packs in one launch
    cvt_w_all<<<dim3(NOUT / 32, 4, 3), 256, 0, stream>>>(P);

    int attn_blocks = (N + 3) / 4;   // 1 wave per node, 4 waves/block
    int gx = (N + 63) / 64;

    const void* xin = x;             // layer 0 reads fp32 x directly
    short* xouts[3] = { xb1, xb2, xb1 };
    for (int l = 0; l < 3; ++l) {
        dim3 ggrid(gx, 7);
        if (l == 0)
            gemm_qkvs_mfma<64, true><<<ggrid, 256, 0, stream>>>(xin, N, P.WT[l], P.bc[l], Qb, KV, Sb);
        else
            gemm_qkvs_mfma<128, false><<<ggrid, 256, 0, stream>>>(xin, N, P.WT[l], P.bc[l], Qb, KV, Sb);
        attn_kernel<<<attn_blocks, 256, 0, stream>>>(Qb, KV, offs, csr, Sb, xouts[l], N);
        xin = xouts[l];
    }

    colsum_kernel<<<256, 128, 0, stream>>>(xb1, g, N);
    final_kernel<<<1, 128, 0, stream>>>(g, Wfc, bfc, (float*)d_out, 1.0f / N);
}